// Round 1
// baseline (766.985 us; speedup 1.0000x reference)
//
#include <hip/hip_runtime.h>

#define RR 48
#define GG 300
#define HW2 (GG * GG)
#define NPLANE (RR * HW2)
#define NVEC (RR * GG)
#define CC 27
#define NBUCK 32768  // 32^3 Morton buckets
#define TP 256       // points per block (one point per thread)

struct Axis { int i0, i1; float f; };

__device__ __forceinline__ Axis axis_interp(float x) {
  float g = x * 2.0f - 1.0f;
  float ih = (g + 1.0f) * 0.5f * (float)(GG - 1);
  int i0 = (int)floorf(ih);
  i0 = i0 < 0 ? 0 : (i0 > GG - 1 ? GG - 1 : i0);
  int i1 = i0 + 1 > GG - 1 ? GG - 1 : i0 + 1;
  Axis a; a.i0 = i0; a.i1 = i1; a.f = ih - (float)i0;
  return a;
}

// ---------------- sort machinery ----------------
__device__ __forceinline__ unsigned part3(unsigned v) {
  unsigned r = 0;
  r |= (v & 1u);
  r |= (v & 2u) << 2;
  r |= (v & 4u) << 4;
  r |= (v & 8u) << 6;
  r |= (v & 16u) << 8;
  return r;
}

__device__ __forceinline__ int morton_key(float x, float y, float z) {
  int qx = (int)(x * 32.0f); qx = qx < 0 ? 0 : (qx > 31 ? 31 : qx);
  int qy = (int)(y * 32.0f); qy = qy < 0 ? 0 : (qy > 31 ? 31 : qy);
  int qz = (int)(z * 32.0f); qz = qz < 0 ? 0 : (qz > 31 ? 31 : qz);
  return (int)(part3((unsigned)qx) | (part3((unsigned)qy) << 1) | (part3((unsigned)qz) << 2));
}

__global__ void __launch_bounds__(256) hist_kernel(const float* __restrict__ xyz, int n,
                                                   int* __restrict__ offs) {
  int i = blockIdx.x * blockDim.x + threadIdx.x;
  if (i >= n) return;
  atomicAdd(&offs[morton_key(xyz[i * 3], xyz[i * 3 + 1], xyz[i * 3 + 2])], 1);
}

__global__ void __launch_bounds__(1024) scan_kernel(int* __restrict__ offs) {
  __shared__ int part[1024];
  int t = threadIdx.x;
  int base = t * (NBUCK / 1024);
  int loc[NBUCK / 1024];
  int s = 0;
#pragma unroll
  for (int i = 0; i < NBUCK / 1024; ++i) { loc[i] = offs[base + i]; s += loc[i]; }
  part[t] = s;
  __syncthreads();
  for (int off = 1; off < 1024; off <<= 1) {
    int u = (t >= off) ? part[t - off] : 0;
    __syncthreads();
    part[t] += u;
    __syncthreads();
  }
  int excl = (t == 0) ? 0 : part[t - 1];
#pragma unroll
  for (int i = 0; i < NBUCK / 1024; ++i) {
    int c = loc[i];
    offs[base + i] = excl;
    excl += c;
  }
}

// Scatter: writes sorted (x,y,z,origIdx) records if sxyz is provided (16B,
// coalesced consumption later), else just the sorted index list.
__global__ void __launch_bounds__(256) scatter_kernel(const float* __restrict__ xyz, int n,
                                                      int* __restrict__ offs,
                                                      int* __restrict__ sidx,
                                                      float4* __restrict__ sxyz) {
  int i = blockIdx.x * blockDim.x + threadIdx.x;
  if (i >= n) return;
  float x = xyz[i * 3], y = xyz[i * 3 + 1], z = xyz[i * 3 + 2];
  int key = morton_key(x, y, z);
  int pos = atomicAdd(&offs[key], 1);
  if (sxyz) {
    sxyz[pos] = make_float4(x, y, z, __int_as_float(i));
  } else {
    sidx[pos] = i;
  }
}

// ---------------- layout transforms ----------------
// [R, HW2] -> [HW2, R], 3 planes via gridDim.y
__global__ void __launch_bounds__(256) transpose_planes(const float* __restrict__ p0,
                                                        const float* __restrict__ p1,
                                                        const float* __restrict__ p2,
                                                        float* __restrict__ t0,
                                                        float* __restrict__ t1,
                                                        float* __restrict__ t2) {
  __shared__ float tile[256 * 49];
  const float* in = (blockIdx.y == 0) ? p0 : (blockIdx.y == 1) ? p1 : p2;
  float* out = (blockIdx.y == 0) ? t0 : (blockIdx.y == 1) ? t1 : t2;
  int base = blockIdx.x * 256;
  int t = threadIdx.x;
  int pos = base + t;
#pragma unroll 1
  for (int r = 0; r < RR; ++r) {
    float v = (pos < HW2) ? in[r * HW2 + pos] : 0.f;
    tile[t * 49 + r] = v;
  }
  __syncthreads();
#pragma unroll 1
  for (int k = t; k < 256 * RR; k += 256) {
    int p = k / RR;
    int r = k - p * RR;
    int hw = base + p;
    if (hw < HW2) out[hw * RR + r] = tile[p * 49 + r];
  }
}

// [R, GG] -> [GG, R], all 3 vecs in one grid
__global__ void __launch_bounds__(256) transpose_vecs(const float* __restrict__ v0,
                                                      const float* __restrict__ v1,
                                                      const float* __restrict__ v2,
                                                      float* __restrict__ t0,
                                                      float* __restrict__ t1,
                                                      float* __restrict__ t2) {
  int e = blockIdx.x * blockDim.x + threadIdx.x;
  if (e >= 3 * NVEC) return;
  int v = e / NVEC;
  int rem = e - v * NVEC;
  int i = rem / RR;
  int r = rem - i * RR;
  const float* in = (v == 0) ? v0 : (v == 1) ? v1 : v2;
  float* out = (v == 0) ? t0 : (v == 1) ? t1 : t2;
  out[i * RR + r] = in[r * GG + i];
}

// ---------------- fused main: one point per thread, no LDS, no barrier ----
// For one segment: 4-corner bilinear * 1D vec interp for all 48 channels,
// FMA'd directly into acc[27] against the matching 48x27 slice of F.
// F reads are wave-uniform -> scalar loads.
__device__ __forceinline__ void seg_accum(const float* __restrict__ P, Axis ai, Axis aj,
                                          const float* __restrict__ V, Axis ak,
                                          const float* __restrict__ Fs,
                                          float* __restrict__ acc) {
  float fi = ai.f, fj = aj.f, fk = ak.f;
  float w00 = (1.f - fi) * (1.f - fj);
  float w01 = (1.f - fi) * fj;
  float w10 = fi * (1.f - fj);
  float w11 = fi * fj;
  float omk = 1.f - fk;
  const float* p00 = P + (ai.i0 * GG + aj.i0) * RR;
  const float* p01 = P + (ai.i0 * GG + aj.i1) * RR;
  const float* p10 = P + (ai.i1 * GG + aj.i0) * RR;
  const float* p11 = P + (ai.i1 * GG + aj.i1) * RR;
  const float* v0 = V + ak.i0 * RR;
  const float* v1 = V + ak.i1 * RR;
#pragma unroll 2
  for (int r4 = 0; r4 < RR / 4; ++r4) {
    float4 q00 = *(const float4*)(p00 + 4 * r4);
    float4 q01 = *(const float4*)(p01 + 4 * r4);
    float4 q10 = *(const float4*)(p10 + 4 * r4);
    float4 q11 = *(const float4*)(p11 + 4 * r4);
    float4 b0 = *(const float4*)(v0 + 4 * r4);
    float4 b1 = *(const float4*)(v1 + 4 * r4);
    float t0 = (w00 * q00.x + w01 * q01.x + w10 * q10.x + w11 * q11.x) * (omk * b0.x + fk * b1.x);
    float t1 = (w00 * q00.y + w01 * q01.y + w10 * q10.y + w11 * q11.y) * (omk * b0.y + fk * b1.y);
    float t2 = (w00 * q00.z + w01 * q01.z + w10 * q10.z + w11 * q11.z) * (omk * b0.z + fk * b1.z);
    float t3 = (w00 * q00.w + w01 * q01.w + w10 * q10.w + w11 * q11.w) * (omk * b0.w + fk * b1.w);
    const float* Fr = Fs + (4 * r4) * CC;
#pragma unroll
    for (int c = 0; c < CC; ++c) {
      acc[c] = fmaf(t3, Fr[3 * CC + c],
               fmaf(t2, Fr[2 * CC + c],
               fmaf(t1, Fr[CC + c],
               fmaf(t0, Fr[c], acc[c]))));
    }
  }
}

__global__ void __launch_bounds__(256, 4) tensorf_point(
    const float4* __restrict__ sxyz, const int* __restrict__ sidx,
    const float* __restrict__ xyz,
    const float* __restrict__ Txy, const float* __restrict__ Txz, const float* __restrict__ Tyz,
    const float* __restrict__ Tx, const float* __restrict__ Ty, const float* __restrict__ Tz,
    const float* __restrict__ F, float* __restrict__ out, int n, int chunkLen) {
  int b = blockIdx.x;
  int nb = (b & 7) * chunkLen + (b >> 3);  // XCD-aware: each XCD streams one Morton chunk
  int sp = nb * TP + threadIdx.x;
  if (sp >= n) return;

  float x, y, z;
  int oi;
  if (sxyz) {
    float4 p4 = sxyz[sp];  // coalesced: sorted records
    x = p4.x; y = p4.y; z = p4.z;
    oi = __float_as_int(p4.w);
  } else {
    oi = sidx[sp];
    x = xyz[oi * 3 + 0];
    y = xyz[oi * 3 + 1];
    z = xyz[oi * 3 + 2];
  }

  Axis ax = axis_interp(x), ay = axis_interp(y), az = axis_interp(z);

  float acc[CC];
#pragma unroll
  for (int c = 0; c < CC; ++c) acc[c] = 0.f;

  seg_accum(Txy, ax, ay, Tz, az, F + 0 * RR * CC, acc);
  seg_accum(Txz, ax, az, Ty, ay, F + 1 * RR * CC, acc);
  seg_accum(Tyz, ay, az, Tx, ax, F + 2 * RR * CC, acc);

  float* o = out + (size_t)oi * CC;
#pragma unroll
  for (int c = 0; c < CC; ++c) o[c] = acc[c];
}

// ---------------- fallback (no workspace) ----------------
__global__ void __launch_bounds__(256) tensorf_naive(
    const float* __restrict__ xyz,
    const float* __restrict__ Pxy, const float* __restrict__ Pxz, const float* __restrict__ Pyz,
    const float* __restrict__ Vx, const float* __restrict__ Vy, const float* __restrict__ Vz,
    const float* __restrict__ F, float* __restrict__ out, int n) {
  int idx = blockIdx.x * blockDim.x + threadIdx.x;
  if (idx >= n) return;
  float x = xyz[idx * 3], y = xyz[idx * 3 + 1], z = xyz[idx * 3 + 2];
  Axis ax = axis_interp(x), ay = axis_interp(y), az = axis_interp(z);
  float acc[CC];
#pragma unroll
  for (int c = 0; c < CC; ++c) acc[c] = 0.f;
  const float* Ps[3] = {Pxy, Pxz, Pyz};
  const float* Vs[3] = {Vz, Vy, Vx};
  Axis A[3][2] = {{ax, ay}, {ax, az}, {ay, az}};
  Axis K[3] = {az, ay, ax};
#pragma unroll 1
  for (int s = 0; s < 3; ++s) {
    Axis ai = A[s][0], aj = A[s][1], ak = K[s];
    float fi = ai.f, fj = aj.f, fk = ak.f;
    float w00 = (1.f - fi) * (1.f - fj), w01 = (1.f - fi) * fj;
    float w10 = fi * (1.f - fj), w11 = fi * fj, omk = 1.f - fk;
#pragma unroll 1
    for (int r = 0; r < RR; ++r) {
      const float* pr = Ps[s] + r * HW2;
      float ft = (w00 * pr[ai.i0 * GG + aj.i0] + w01 * pr[ai.i0 * GG + aj.i1] +
                  w10 * pr[ai.i1 * GG + aj.i0] + w11 * pr[ai.i1 * GG + aj.i1]) *
                 (omk * Vs[s][r * GG + ak.i0] + fk * Vs[s][r * GG + ak.i1]);
      const float* Fr = F + (s * RR + r) * CC;
#pragma unroll
      for (int c = 0; c < CC; ++c) acc[c] = fmaf(ft, Fr[c], acc[c]);
    }
  }
  float* o = out + (size_t)idx * CC;
#pragma unroll
  for (int c = 0; c < CC; ++c) o[c] = acc[c];
}

extern "C" void kernel_launch(void* const* d_in, const int* in_sizes, int n_in,
                              void* d_out, int out_size, void* d_ws, size_t ws_size,
                              hipStream_t stream) {
  const float* xyz = (const float*)d_in[0];
  const float* pxy = (const float*)d_in[1];
  const float* pxz = (const float*)d_in[2];
  const float* pyz = (const float*)d_in[3];
  const float* vx = (const float*)d_in[4];
  const float* vy = (const float*)d_in[5];
  const float* vz = (const float*)d_in[6];
  const float* F = (const float*)d_in[7];
  float* out = (float*)d_out;
  int n = in_sizes[0] / 3;
  int nblk = (n + 255) / 256;

  size_t fixed = (size_t)(3 * NPLANE + 3 * NVEC) * sizeof(float) +
                 (size_t)NBUCK * sizeof(int);
  size_t need1 = fixed + (size_t)n * sizeof(int);      // sorted-index variant
  size_t need2 = fixed + (size_t)n * sizeof(float4);   // sorted-record variant

  if (ws_size >= need1) {
    float* w = (float*)d_ws;
    float* Txy = w;
    float* Txz = Txy + NPLANE;
    float* Tyz = Txz + NPLANE;
    float* Tx = Tyz + NPLANE;
    float* Ty = Tx + NVEC;
    float* Tz = Ty + NVEC;
    int* offs = (int*)(Tz + NVEC);

    int* sidx = nullptr;
    float4* sxyz = nullptr;
    if (ws_size >= need2) sxyz = (float4*)(offs + NBUCK);
    else sidx = (int*)(offs + NBUCK);

    int tb = (HW2 + 255) / 256;
    dim3 tg(tb, 3);
    transpose_planes<<<tg, 256, 0, stream>>>(pxy, pxz, pyz, Txy, Txz, Tyz);
    int vb = (3 * NVEC + 255) / 256;
    transpose_vecs<<<vb, 256, 0, stream>>>(vx, vy, vz, Tx, Ty, Tz);

    hipMemsetAsync(offs, 0, (size_t)NBUCK * sizeof(int), stream);
    hist_kernel<<<nblk, 256, 0, stream>>>(xyz, n, offs);
    scan_kernel<<<1, 1024, 0, stream>>>(offs);
    scatter_kernel<<<nblk, 256, 0, stream>>>(xyz, n, offs, sidx, sxyz);

    int ntile = (n + TP - 1) / TP;
    int chunkLen = (ntile + 7) / 8;
    tensorf_point<<<chunkLen * 8, 256, 0, stream>>>(sxyz, sidx, xyz, Txy, Txz, Tyz,
                                                    Tx, Ty, Tz, F, out, n, chunkLen);
  } else {
    tensorf_naive<<<nblk, 256, 0, stream>>>(xyz, pxy, pxz, pyz, vx, vy, vz, F, out, n);
  }
}